// Round 5
// baseline (108.886 us; speedup 1.0000x reference)
//
#include <hip/hip_runtime.h>
#include <hip/hip_bf16.h>
#include <math.h>

#define H_HEADS 16
#define DMODEL  1024
#define DHEAD   64
#define LSEQ    1024
#define CHUNK   64
#define NCHUNK  16
#define EPS_F   1e-6f

typedef __attribute__((ext_vector_type(8))) short bf16x8;   // 8 bf16 = 4 VGPRs
typedef __attribute__((ext_vector_type(4))) float f32x4;    // MFMA 16x16 accumulator

__device__ inline unsigned short f2bf(float f) {
    unsigned int u = __float_as_uint(f);
    u += 0x7FFF + ((u >> 16) & 1);          // round-to-nearest-even
    return (unsigned short)(u >> 16);
}
__device__ inline float bf2f(unsigned short h) {
    return __uint_as_float(((unsigned int)h) << 16);
}

#define LDA 40   // LDS row stride in bf16 elems (80B: 16B-aligned, conflict-reduced)

// =====================================================================
// fp32 -> bf16 convert: q,k,v -> Xb[3][2M]; Wq,Wk,Wv,Wo -> Wb[4][1M].
// =====================================================================
__global__ __launch_bounds__(256)
void convert_kernel(const float* __restrict__ q, const float* __restrict__ k,
                    const float* __restrict__ v,
                    const float* __restrict__ Wq, const float* __restrict__ Wk,
                    const float* __restrict__ Wv, const float* __restrict__ Wo,
                    unsigned short* __restrict__ Xb, unsigned short* __restrict__ Wb)
{
    const int y = blockIdx.y;
    const float* src;
    unsigned short* dst;
    int n;
    if (y < 3) {
        src = (y == 0) ? q : (y == 1) ? k : v;
        dst = Xb + (size_t)y * (2 * LSEQ * DMODEL);
        n = 2 * LSEQ * DMODEL;
    } else {
        int w = y - 3;
        src = (w == 0) ? Wq : (w == 1) ? Wk : (w == 2) ? Wv : Wo;
        dst = Wb + (size_t)w * (DMODEL * DMODEL);
        n = DMODEL * DMODEL;
    }
    int idx = (blockIdx.x * 256 + threadIdx.x) * 4;
    if (idx < n) {
        float4 f = *(const float4*)(src + idx);
        ushort4 h = make_ushort4(f2bf(f.x), f2bf(f.y), f2bf(f.z), f2bf(f.w));
        *(ushort4*)(dst + idx) = h;
    }
}

// =====================================================================
// bf16 MFMA projection GEMM: O = phi(X @ W^T * sc) -> bf16 [B,H,L,d].
// 128x128 tile, BK=32, 4 waves (2x2 of 64x64), 4x4 fragments/wave.
// grid = (8, 16, 3).
// =====================================================================
__global__ __launch_bounds__(256)
void proj_bf16_kernel(const unsigned short* __restrict__ Xb,
                      const unsigned short* __restrict__ Wb,
                      unsigned short* __restrict__ qp, unsigned short* __restrict__ kp,
                      unsigned short* __restrict__ vp)
{
    const int z = blockIdx.z;
    const unsigned short* X = Xb + (size_t)z * (2 * LSEQ * DMODEL);
    const unsigned short* W = Wb + (size_t)z * (DMODEL * DMODEL);
    unsigned short* O = (z == 0) ? qp : (z == 1) ? kp : vp;

    __shared__ unsigned short As[128 * LDA];
    __shared__ unsigned short Bs[128 * LDA];

    const int tid  = threadIdx.x;
    const int m0   = blockIdx.y * 128;
    const int n0   = blockIdx.x * 128;
    const int lane = tid & 63;
    const int wid  = tid >> 6;
    const int wm   = (wid >> 1) * 64;
    const int wn   = (wid & 1) * 64;
    const int r16  = lane & 15;
    const int qh   = lane >> 4;

    f32x4 acc[4][4];
#pragma unroll
    for (int i = 0; i < 4; ++i)
#pragma unroll
        for (int j = 0; j < 4; ++j) acc[i][j] = (f32x4)0.0f;

    for (int kt = 0; kt < DMODEL; kt += 32) {
#pragma unroll
        for (int i = 0; i < 2; ++i) {
            int id  = tid + i * 256;        // 0..511
            int row = id >> 2;              // 0..127
            int cg  = (id & 3) * 8;         // 0,8,16,24
            *(bf16x8*)&As[row * LDA + cg] =
                *(const bf16x8*)(X + (size_t)(m0 + row) * DMODEL + kt + cg);
            *(bf16x8*)&Bs[row * LDA + cg] =
                *(const bf16x8*)(W + (size_t)(n0 + row) * DMODEL + kt + cg);
        }
        __syncthreads();

        bf16x8 af[4], bg[4];
#pragma unroll
        for (int fm = 0; fm < 4; ++fm)
            af[fm] = *(const bf16x8*)&As[(wm + fm * 16 + r16) * LDA + qh * 8];
#pragma unroll
        for (int fn = 0; fn < 4; ++fn)
            bg[fn] = *(const bf16x8*)&Bs[(wn + fn * 16 + r16) * LDA + qh * 8];
#pragma unroll
        for (int fm = 0; fm < 4; ++fm)
#pragma unroll
            for (int fn = 0; fn < 4; ++fn)
                acc[fm][fn] = __builtin_amdgcn_mfma_f32_16x16x32_bf16(
                    af[fm], bg[fn], acc[fm][fn], 0, 0, 0);
        __syncthreads();
    }

    const float sc = (z < 2) ? 0.125f : 1.f;
#pragma unroll
    for (int fm = 0; fm < 4; ++fm) {
#pragma unroll
        for (int r = 0; r < 4; ++r) {
            int m = m0 + wm + fm * 16 + qh * 4 + r;
            int b = m >> 10, l = m & 1023;
#pragma unroll
            for (int fn = 0; fn < 4; ++fn) {
                int n = n0 + wn + fn * 16 + r16;
                int h = n >> 6, e = n & 63;
                float y = acc[fm][fn][r] * sc;
                if (z < 2) y = (y > 0.f) ? y + 1.f : __expf(y);
                O[(((size_t)(b * H_HEADS + h)) * LSEQ + l) * DHEAD + e] = f2bf(y);
            }
        }
    }
}

// =====================================================================
// bf16 MFMA output GEMM: out = attb @ Wo^T (fp32 out). 128x128 tile.
// grid = (8, 16).
// =====================================================================
__global__ __launch_bounds__(256)
void gemm_out_bf16_kernel(const unsigned short* __restrict__ A,
                          const unsigned short* __restrict__ W,
                          float* __restrict__ out)
{
    __shared__ unsigned short As[128 * LDA];
    __shared__ unsigned short Bs[128 * LDA];

    const int tid  = threadIdx.x;
    const int m0   = blockIdx.y * 128;
    const int n0   = blockIdx.x * 128;
    const int lane = tid & 63;
    const int wid  = tid >> 6;
    const int wm   = (wid >> 1) * 64;
    const int wn   = (wid & 1) * 64;
    const int r16  = lane & 15;
    const int qh   = lane >> 4;

    f32x4 acc[4][4];
#pragma unroll
    for (int i = 0; i < 4; ++i)
#pragma unroll
        for (int j = 0; j < 4; ++j) acc[i][j] = (f32x4)0.0f;

    for (int kt = 0; kt < DMODEL; kt += 32) {
#pragma unroll
        for (int i = 0; i < 2; ++i) {
            int id  = tid + i * 256;
            int row = id >> 2;
            int cg  = (id & 3) * 8;
            *(bf16x8*)&As[row * LDA + cg] =
                *(const bf16x8*)(A + (size_t)(m0 + row) * DMODEL + kt + cg);
            *(bf16x8*)&Bs[row * LDA + cg] =
                *(const bf16x8*)(W + (size_t)(n0 + row) * DMODEL + kt + cg);
        }
        __syncthreads();

        bf16x8 af[4], bg[4];
#pragma unroll
        for (int fm = 0; fm < 4; ++fm)
            af[fm] = *(const bf16x8*)&As[(wm + fm * 16 + r16) * LDA + qh * 8];
#pragma unroll
        for (int fn = 0; fn < 4; ++fn)
            bg[fn] = *(const bf16x8*)&Bs[(wn + fn * 16 + r16) * LDA + qh * 8];
#pragma unroll
        for (int fm = 0; fm < 4; ++fm)
#pragma unroll
            for (int fn = 0; fn < 4; ++fn)
                acc[fm][fn] = __builtin_amdgcn_mfma_f32_16x16x32_bf16(
                    af[fm], bg[fn], acc[fm][fn], 0, 0, 0);
        __syncthreads();
    }

#pragma unroll
    for (int fm = 0; fm < 4; ++fm) {
#pragma unroll
        for (int r = 0; r < 4; ++r) {
            int m = m0 + wm + fm * 16 + qh * 4 + r;
#pragma unroll
            for (int fn = 0; fn < 4; ++fn) {
                int n = n0 + wn + fn * 16 + r16;
                out[(size_t)m * DMODEL + n] = acc[fm][fn][r];
            }
        }
    }
}

// =====================================================================
// Per-chunk KV outer-product sums; kp/vp are bf16 now.
// =====================================================================
__global__ __launch_bounds__(256)
void chunk_kv_kernel(const unsigned short* __restrict__ kp,
                     const unsigned short* __restrict__ vp,
                     float* __restrict__ S, float* __restrict__ z, int NC)
{
    const int c = blockIdx.x, bh = blockIdx.y;
    const int tid = threadIdx.x;
    const int txx = tid & 15, tyy = tid >> 4;

    __shared__ float ks[64][64];
    __shared__ float vs[64][64];

    const size_t base = ((size_t)bh * LSEQ + (size_t)c * CHUNK) * DHEAD;
#pragma unroll
    for (int i = 0; i < 2; ++i) {
        int id  = tid + i * 256;        // 0..511
        int row = id >> 3;              // 0..63
        int cg  = (id & 7) * 8;         // 0..56
        bf16x8 kv = *(const bf16x8*)(kp + base + row * 64 + cg);
        bf16x8 vv = *(const bf16x8*)(vp + base + row * 64 + cg);
#pragma unroll
        for (int j = 0; j < 8; ++j) {
            ks[row][cg + j] = bf2f((unsigned short)kv[j]);
            vs[row][cg + j] = bf2f((unsigned short)vv[j]);
        }
    }
    __syncthreads();

    float acc[4][4];
#pragma unroll
    for (int i = 0; i < 4; ++i)
#pragma unroll
        for (int j = 0; j < 4; ++j) acc[i][j] = 0.f;

    for (int t = 0; t < 64; ++t) {
        float a[4];
        float4 b4 = *(const float4*)&vs[t][txx * 4];
#pragma unroll
        for (int ii = 0; ii < 4; ++ii) a[ii] = ks[t][tyy * 4 + ii];
#pragma unroll
        for (int ii = 0; ii < 4; ++ii) {
            acc[ii][0] = fmaf(a[ii], b4.x, acc[ii][0]);
            acc[ii][1] = fmaf(a[ii], b4.y, acc[ii][1]);
            acc[ii][2] = fmaf(a[ii], b4.z, acc[ii][2]);
            acc[ii][3] = fmaf(a[ii], b4.w, acc[ii][3]);
        }
    }

    const size_t sbase = ((size_t)bh * NC + c) * (DHEAD * DHEAD);
#pragma unroll
    for (int ii = 0; ii < 4; ++ii) {
        int i = tyy * 4 + ii;
        *(float4*)&S[sbase + (size_t)i * 64 + txx * 4] =
            make_float4(acc[ii][0], acc[ii][1], acc[ii][2], acc[ii][3]);
    }

    if (tid < 64) {
        float s = 0.f;
        for (int t = 0; t < 64; ++t) s += ks[t][tid];
        z[((size_t)bh * NC + c) * 64 + tid] = s;
    }
}

// =====================================================================
// Exclusive prefix over chunks — parallel (unchanged).
// =====================================================================
__global__ __launch_bounds__(256)
void prefix_kernel(float* __restrict__ S, float* __restrict__ z, int NC)
{
    const int bh   = blockIdx.x >> 4;
    const int eblk = blockIdx.x & 15;
    const int e    = eblk * 256 + threadIdx.x;

    const size_t base = (size_t)bh * NCHUNK * (DHEAD * DHEAD) + e;
    float v[NCHUNK];
#pragma unroll
    for (int c = 0; c < NCHUNK; ++c)
        v[c] = S[base + (size_t)c * (DHEAD * DHEAD)];
    float run = 0.f;
#pragma unroll
    for (int c = 0; c < NCHUNK; ++c) {
        S[base + (size_t)c * (DHEAD * DHEAD)] = run;
        run += v[c];
    }

    if (eblk == 0 && threadIdx.x < DHEAD) {
        const size_t zb = (size_t)bh * NCHUNK * DHEAD + threadIdx.x;
        float zv[NCHUNK];
#pragma unroll
        for (int c = 0; c < NCHUNK; ++c)
            zv[c] = z[zb + (size_t)c * DHEAD];
        float zr = 0.f;
#pragma unroll
        for (int c = 0; c < NCHUNK; ++c) {
            z[zb + (size_t)c * DHEAD] = zr;
            zr += zv[c];
        }
    }
}

// =====================================================================
// Per-chunk causal attention; qp/kp/vp bf16 in, att bf16 out.
// =====================================================================
__global__ __launch_bounds__(256)
void attn_chunk_kernel(const unsigned short* __restrict__ qp,
                       const unsigned short* __restrict__ kp,
                       const unsigned short* __restrict__ vp,
                       const float* __restrict__ Spre, const float* __restrict__ zpre,
                       unsigned short* __restrict__ att, int NC)
{
    const int c = blockIdx.x, bh = blockIdx.y;
    const int b = bh >> 4, h = bh & 15;
    const int tid = threadIdx.x;
    const int txx = tid & 15, tyy = tid >> 4;

    __shared__ float qs[64][64];
    __shared__ float ks[64][64];   // Kp, later reused for V
    __shared__ float ss[64][64];   // Sprev
    __shared__ float ps[64][64];   // masked P

    const size_t base = ((size_t)bh * LSEQ + (size_t)c * CHUNK) * DHEAD;
    const size_t sbase = ((size_t)bh * NC + c) * (DHEAD * DHEAD);
    const float* zp = zpre + ((size_t)bh * NC + c) * 64;

#pragma unroll
    for (int i = 0; i < 2; ++i) {
        int id  = tid + i * 256;
        int row = id >> 3;
        int cg  = (id & 7) * 8;
        bf16x8 qv = *(const bf16x8*)(qp + base + row * 64 + cg);
        bf16x8 kv = *(const bf16x8*)(kp + base + row * 64 + cg);
#pragma unroll
        for (int j = 0; j < 8; ++j) {
            qs[row][cg + j] = bf2f((unsigned short)qv[j]);
            ks[row][cg + j] = bf2f((unsigned short)kv[j]);
        }
    }
#pragma unroll
    for (int i = 0; i < 4; ++i) {
        int f = tid + i * 256;
        int row = f >> 4, qd = (f & 15) * 4;
        *(float4*)&ss[row][qd] = *(const float4*)(Spre + sbase + row * 64 + qd);
    }
    __syncthreads();

    float oacc[4][4], pacc[4][4], den[4];
#pragma unroll
    for (int i = 0; i < 4; ++i) {
        den[i] = 0.f;
#pragma unroll
        for (int j = 0; j < 4; ++j) { oacc[i][j] = 0.f; pacc[i][j] = 0.f; }
    }

    for (int k = 0; k < 64; ++k) {
        float a[4], bb[4];
        float4 s4 = *(const float4*)&ss[k][txx * 4];
        float zk = zp[k];
#pragma unroll
        for (int ii = 0; ii < 4; ++ii) a[ii] = qs[tyy * 4 + ii][k];
#pragma unroll
        for (int jj = 0; jj < 4; ++jj) bb[jj] = ks[txx * 4 + jj][k];
#pragma unroll
        for (int ii = 0; ii < 4; ++ii) {
            den[ii] = fmaf(a[ii], zk, den[ii]);
            oacc[ii][0] = fmaf(a[ii], s4.x, oacc[ii][0]);
            oacc[ii][1] = fmaf(a[ii], s4.y, oacc[ii][1]);
            oacc[ii][2] = fmaf(a[ii], s4.z, oacc[ii][2]);
            oacc[ii][3] = fmaf(a[ii], s4.w, oacc[ii][3]);
#pragma unroll
            for (int jj = 0; jj < 4; ++jj)
                pacc[ii][jj] = fmaf(a[ii], bb[jj], pacc[ii][jj]);
        }
    }

#pragma unroll
    for (int ii = 0; ii < 4; ++ii) {
        int t = tyy * 4 + ii;
#pragma unroll
        for (int jj = 0; jj < 4; ++jj) {
            int s = txx * 4 + jj;
            ps[t][s] = (s <= t) ? pacc[ii][jj] : 0.f;
        }
    }
    __syncthreads();

    // reload V into ks
#pragma unroll
    for (int i = 0; i < 2; ++i) {
        int id  = tid + i * 256;
        int row = id >> 3;
        int cg  = (id & 7) * 8;
        bf16x8 vv = *(const bf16x8*)(vp + base + row * 64 + cg);
#pragma unroll
        for (int j = 0; j < 8; ++j)
            ks[row][cg + j] = bf2f((unsigned short)vv[j]);
    }
    __syncthreads();

    for (int s = 0; s < 64; ++s) {
        float4 v4 = *(const float4*)&ks[s][txx * 4];
#pragma unroll
        for (int ii = 0; ii < 4; ++ii) {
            float p = ps[tyy * 4 + ii][s];
            den[ii] += p;
            oacc[ii][0] = fmaf(p, v4.x, oacc[ii][0]);
            oacc[ii][1] = fmaf(p, v4.y, oacc[ii][1]);
            oacc[ii][2] = fmaf(p, v4.z, oacc[ii][2]);
            oacc[ii][3] = fmaf(p, v4.w, oacc[ii][3]);
        }
    }

#pragma unroll
    for (int ii = 0; ii < 4; ++ii) {
        int t = tyy * 4 + ii;
        int l = c * CHUNK + t;
        float inv = 1.f / (den[ii] + EPS_F);
#pragma unroll
        for (int jj = 0; jj < 4; ++jj) {
            int e = txx * 4 + jj;
            att[((size_t)b * LSEQ + l) * DMODEL + h * DHEAD + e] =
                f2bf(oacc[ii][jj] * inv);
        }
    }
}

// =====================================================================
extern "C" void kernel_launch(void* const* d_in, const int* in_sizes, int n_in,
                              void* d_out, int out_size, void* d_ws, size_t ws_size,
                              hipStream_t stream)
{
    const float* query = (const float*)d_in[0];
    const float* key_  = (const float*)d_in[1];
    const float* value = (const float*)d_in[2];
    const float* Wq = (const float*)d_in[3];
    const float* Wk = (const float*)d_in[4];
    const float* Wv = (const float*)d_in[5];
    const float* Wo = (const float*)d_in[6];
    float* out = (float*)d_out;

    const int M  = 2 * LSEQ;     // 2048
    const int BH = 2 * H_HEADS;  // 32
    const int NC = NCHUNK;       // 16

    // ws layout (bytes):
    //   [0,        8.4M)   Wb   : bf16 Wq|Wk|Wv|Wo      4 x 1M x 2B
    //   [8.4M,    21.0M)   qp,kp,vp : bf16 [B,H,L,d]    3 x 2M x 2B
    //   [21.0M,   25.2M)   attb : bf16 [M,1024]         2M x 2B
    //   [25.2M,   37.8M)   Xb   : bf16 q|k|v (dead after proj)
    //   [25.2M,   33.7M)   S,z  : fp32 (alias Xb; written after proj)
    char* wsb = (char*)d_ws;
    unsigned short* Wb   = (unsigned short*)(wsb);
    unsigned short* qp   = (unsigned short*)(wsb + 8388608);
    unsigned short* kp   = (unsigned short*)(wsb + 12582912);
    unsigned short* vp   = (unsigned short*)(wsb + 16777216);
    unsigned short* attb = (unsigned short*)(wsb + 20971520);
    unsigned short* Xb   = (unsigned short*)(wsb + 25165824);
    float*          S    = (float*)(wsb + 25165824);
    float*          z    = (float*)(wsb + 33554432);

    dim3 blk(256);
    convert_kernel<<<dim3(2048, 7), blk, 0, stream>>>(
        query, key_, value, Wq, Wk, Wv, Wo, Xb, Wb);
    proj_bf16_kernel<<<dim3(DMODEL / 128, M / 128, 3), blk, 0, stream>>>(
        Xb, Wb, qp, kp, vp);
    chunk_kv_kernel<<<dim3(NC, BH), blk, 0, stream>>>(kp, vp, S, z, NC);
    prefix_kernel<<<dim3(BH * 16), blk, 0, stream>>>(S, z, NC);
    attn_chunk_kernel<<<dim3(NC, BH), blk, 0, stream>>>(qp, kp, vp, S, z, attb, NC);
    gemm_out_bf16_kernel<<<dim3(DMODEL / 128, M / 128), blk, 0, stream>>>(
        attb, Wb + 3 * (size_t)DMODEL * DMODEL, out);
}

// Round 6
// 92.882 us; speedup vs baseline: 1.1723x; 1.1723x over previous
//
#include <hip/hip_runtime.h>
#include <hip/hip_bf16.h>
#include <math.h>

#define H_HEADS 16
#define DMODEL  1024
#define DHEAD   64
#define LSEQ    1024
#define CHUNK   64
#define NCHUNK  16
#define EPS_F   1e-6f

typedef __attribute__((ext_vector_type(8))) short bf16x8;   // 8 bf16 = 4 VGPRs
typedef __attribute__((ext_vector_type(4))) float f32x4;    // MFMA 16x16 accumulator

__device__ inline unsigned short f2bf(float f) {
    unsigned int u = __float_as_uint(f);
    u += 0x7FFF + ((u >> 16) & 1);          // round-to-nearest-even
    return (unsigned short)(u >> 16);
}
__device__ inline float bf2f(unsigned short h) {
    return __uint_as_float(((unsigned int)h) << 16);
}

// async global->LDS, 16B per lane. LDS dest = wave-uniform base + lane*16.
#define GLOAD16(g, l) __builtin_amdgcn_global_load_lds( \
    (const __attribute__((address_space(1))) void*)(g), \
    (__attribute__((address_space(3))) void*)(l), 16, 0, 0)

// =====================================================================
// fp32 -> bf16 convert: q,k,v -> Xb[3][2M]; Wq,Wk,Wv,Wo -> Wb[4][1M].
// =====================================================================
__global__ __launch_bounds__(256)
void convert_kernel(const float* __restrict__ q, const float* __restrict__ k,
                    const float* __restrict__ v,
                    const float* __restrict__ Wq, const float* __restrict__ Wk,
                    const float* __restrict__ Wv, const float* __restrict__ Wo,
                    unsigned short* __restrict__ Xb, unsigned short* __restrict__ Wb)
{
    const int y = blockIdx.y;
    const float* src;
    unsigned short* dst;
    int n;
    if (y < 3) {
        src = (y == 0) ? q : (y == 1) ? k : v;
        dst = Xb + (size_t)y * (2 * LSEQ * DMODEL);
        n = 2 * LSEQ * DMODEL;
    } else {
        int w = y - 3;
        src = (w == 0) ? Wq : (w == 1) ? Wk : (w == 2) ? Wv : Wo;
        dst = Wb + (size_t)w * (DMODEL * DMODEL);
        n = DMODEL * DMODEL;
    }
    int idx = (blockIdx.x * 256 + threadIdx.x) * 4;
    if (idx < n) {
        float4 f = *(const float4*)(src + idx);
        ushort4 h = make_ushort4(f2bf(f.x), f2bf(f.y), f2bf(f.z), f2bf(f.w));
        *(ushort4*)(dst + idx) = h;
    }
}

// =====================================================================
// bf16 MFMA GEMM core (m97-style): BM=64, BN=128, BK=32, 4 waves (2x2 of
// 32x64), linear LDS (A 4KB, B 8KB), global_load_lds width-16 staging.
// PROJ: epilogue scale+elu+1 (z<2), store bf16 [B,H,L,d].
// !PROJ: store fp32 row-major.
// =====================================================================
template<bool PROJ>
__global__ __launch_bounds__(256)
void mfma_gemm64_kernel(const unsigned short* __restrict__ Xb,
                        const unsigned short* __restrict__ Wb,
                        unsigned short* __restrict__ qp,
                        unsigned short* __restrict__ kp,
                        unsigned short* __restrict__ vp,
                        float* __restrict__ outf)
{
    const int z = PROJ ? blockIdx.z : 0;
    const unsigned short* X = PROJ ? (Xb + (size_t)z * (2 * LSEQ * DMODEL)) : Xb;
    const unsigned short* W = PROJ ? (Wb + (size_t)z * (DMODEL * DMODEL)) : Wb;

    __shared__ unsigned short As[64 * 32];    // 4 KB, row stride 32 bf16 (64B)
    __shared__ unsigned short Bs[128 * 32];   // 8 KB

    const int tid  = threadIdx.x;
    const int m0   = blockIdx.y * 64;
    const int n0   = blockIdx.x * 128;
    const int lane = tid & 63;
    const int wid  = tid >> 6;
    const int wm   = (wid >> 1) * 32;
    const int wn   = (wid & 1) * 64;
    const int r16  = lane & 15;
    const int qh   = lane >> 4;

    // staging: wave wid owns As[wid*1KB] and Bs[wid*2KB]
    const int rA  = wid * 16 + (lane >> 2);        // 0..63
    const int rB0 = wid * 32 + (lane >> 2);        // 0..127 (two halves)
    const int c16 = lane & 3;                      // 16B slot in 64B row
    const char* srcA  = (const char*)(X + (size_t)(m0 + rA)  * DMODEL) + c16 * 16;
    const char* srcB0 = (const char*)(W + (size_t)(n0 + rB0) * DMODEL) + c16 * 16;
    const char* srcB1 = (const char*)(W + (size_t)(n0 + rB0 + 16) * DMODEL) + c16 * 16;
    unsigned short* dstA  = As + wid * 512;
    unsigned short* dstB0 = Bs + wid * 1024;
    unsigned short* dstB1 = Bs + wid * 1024 + 512;

    f32x4 acc[2][4];
#pragma unroll
    for (int i = 0; i < 2; ++i)
#pragma unroll
        for (int j = 0; j < 4; ++j) acc[i][j] = (f32x4)0.0f;

    for (int kt = 0; kt < DMODEL; kt += 32) {
        GLOAD16(srcA  + (size_t)kt * 2, dstA);
        GLOAD16(srcB0 + (size_t)kt * 2, dstB0);
        GLOAD16(srcB1 + (size_t)kt * 2, dstB1);
        __syncthreads();   // vmcnt(0) drain -> data ready

        bf16x8 af[2], bg[4];
#pragma unroll
        for (int fm = 0; fm < 2; ++fm)
            af[fm] = *(const bf16x8*)&As[(wm + fm * 16 + r16) * 32 + qh * 8];
#pragma unroll
        for (int fn = 0; fn < 4; ++fn)
            bg[fn] = *(const bf16x8*)&Bs[(wn + fn * 16 + r16) * 32 + qh * 8];
#pragma unroll
        for (int fm = 0; fm < 2; ++fm)
#pragma unroll
            for (int fn = 0; fn < 4; ++fn)
                acc[fm][fn] = __builtin_amdgcn_mfma_f32_16x16x32_bf16(
                    af[fm], bg[fn], acc[fm][fn], 0, 0, 0);
        __syncthreads();
    }

    if (PROJ) {
        unsigned short* O = (z == 0) ? qp : (z == 1) ? kp : vp;
        const float sc = (z < 2) ? 0.125f : 1.f;
#pragma unroll
        for (int fm = 0; fm < 2; ++fm) {
#pragma unroll
            for (int r = 0; r < 4; ++r) {
                int m = m0 + wm + fm * 16 + qh * 4 + r;
                int b = m >> 10, l = m & 1023;
#pragma unroll
                for (int fn = 0; fn < 4; ++fn) {
                    int n = n0 + wn + fn * 16 + r16;
                    int h = n >> 6, e = n & 63;
                    float y = acc[fm][fn][r] * sc;
                    if (z < 2) y = (y > 0.f) ? y + 1.f : __expf(y);
                    O[(((size_t)(b * H_HEADS + h)) * LSEQ + l) * DHEAD + e] = f2bf(y);
                }
            }
        }
    } else {
#pragma unroll
        for (int fm = 0; fm < 2; ++fm) {
#pragma unroll
            for (int r = 0; r < 4; ++r) {
                int m = m0 + wm + fm * 16 + qh * 4 + r;
#pragma unroll
                for (int fn = 0; fn < 4; ++fn) {
                    int n = n0 + wn + fn * 16 + r16;
                    outf[(size_t)m * DMODEL + n] = acc[fm][fn][r];
                }
            }
        }
    }
}

// =====================================================================
// Per-chunk KV outer-product sums; kp/vp bf16.
// =====================================================================
__global__ __launch_bounds__(256)
void chunk_kv_kernel(const unsigned short* __restrict__ kp,
                     const unsigned short* __restrict__ vp,
                     float* __restrict__ S, float* __restrict__ z, int NC)
{
    const int c = blockIdx.x, bh = blockIdx.y;
    const int tid = threadIdx.x;
    const int txx = tid & 15, tyy = tid >> 4;

    __shared__ float ks[64][64];
    __shared__ float vs[64][64];

    const size_t base = ((size_t)bh * LSEQ + (size_t)c * CHUNK) * DHEAD;
#pragma unroll
    for (int i = 0; i < 2; ++i) {
        int id  = tid + i * 256;        // 0..511
        int row = id >> 3;              // 0..63
        int cg  = (id & 7) * 8;         // 0..56
        bf16x8 kv = *(const bf16x8*)(kp + base + row * 64 + cg);
        bf16x8 vv = *(const bf16x8*)(vp + base + row * 64 + cg);
#pragma unroll
        for (int j = 0; j < 8; ++j) {
            ks[row][cg + j] = bf2f((unsigned short)kv[j]);
            vs[row][cg + j] = bf2f((unsigned short)vv[j]);
        }
    }
    __syncthreads();

    float acc[4][4];
#pragma unroll
    for (int i = 0; i < 4; ++i)
#pragma unroll
        for (int j = 0; j < 4; ++j) acc[i][j] = 0.f;

    for (int t = 0; t < 64; ++t) {
        float a[4];
        float4 b4 = *(const float4*)&vs[t][txx * 4];
#pragma unroll
        for (int ii = 0; ii < 4; ++ii) a[ii] = ks[t][tyy * 4 + ii];
#pragma unroll
        for (int ii = 0; ii < 4; ++ii) {
            acc[ii][0] = fmaf(a[ii], b4.x, acc[ii][0]);
            acc[ii][1] = fmaf(a[ii], b4.y, acc[ii][1]);
            acc[ii][2] = fmaf(a[ii], b4.z, acc[ii][2]);
            acc[ii][3] = fmaf(a[ii], b4.w, acc[ii][3]);
        }
    }

    const size_t sbase = ((size_t)bh * NC + c) * (DHEAD * DHEAD);
#pragma unroll
    for (int ii = 0; ii < 4; ++ii) {
        int i = tyy * 4 + ii;
        *(float4*)&S[sbase + (size_t)i * 64 + txx * 4] =
            make_float4(acc[ii][0], acc[ii][1], acc[ii][2], acc[ii][3]);
    }

    if (tid < 64) {
        float s = 0.f;
        for (int t = 0; t < 64; ++t) s += ks[t][tid];
        z[((size_t)bh * NC + c) * 64 + tid] = s;
    }
}

// =====================================================================
// Exclusive prefix over chunks — parallel (unchanged).
// =====================================================================
__global__ __launch_bounds__(256)
void prefix_kernel(float* __restrict__ S, float* __restrict__ z, int NC)
{
    const int bh   = blockIdx.x >> 4;
    const int eblk = blockIdx.x & 15;
    const int e    = eblk * 256 + threadIdx.x;

    const size_t base = (size_t)bh * NCHUNK * (DHEAD * DHEAD) + e;
    float v[NCHUNK];
#pragma unroll
    for (int c = 0; c < NCHUNK; ++c)
        v[c] = S[base + (size_t)c * (DHEAD * DHEAD)];
    float run = 0.f;
#pragma unroll
    for (int c = 0; c < NCHUNK; ++c) {
        S[base + (size_t)c * (DHEAD * DHEAD)] = run;
        run += v[c];
    }

    if (eblk == 0 && threadIdx.x < DHEAD) {
        const size_t zb = (size_t)bh * NCHUNK * DHEAD + threadIdx.x;
        float zv[NCHUNK];
#pragma unroll
        for (int c = 0; c < NCHUNK; ++c)
            zv[c] = z[zb + (size_t)c * DHEAD];
        float zr = 0.f;
#pragma unroll
        for (int c = 0; c < NCHUNK; ++c) {
            z[zb + (size_t)c * DHEAD] = zr;
            zr += zv[c];
        }
    }
}

// =====================================================================
// Per-chunk causal attention; bank-conflict-free LDS layout:
//   qT/kT transposed [64][65] (stride-65: scalar r/w are ~2-way max),
//   ss row-major [64][64] (float4, 2-way), ps [64][68] scalar.
//   kT is reused row-major for V in the PV phase.
// =====================================================================
__global__ __launch_bounds__(256)
void attn_chunk_kernel(const unsigned short* __restrict__ qp,
                       const unsigned short* __restrict__ kp,
                       const unsigned short* __restrict__ vp,
                       const float* __restrict__ Spre, const float* __restrict__ zpre,
                       unsigned short* __restrict__ att, int NC)
{
    const int c = blockIdx.x, bh = blockIdx.y;
    const int b = bh >> 4, h = bh & 15;
    const int tid = threadIdx.x;
    const int txx = tid & 15, tyy = tid >> 4;

    __shared__ float qT[64][65];   // qT[k][t]  (transposed)
    __shared__ float kT[64][65];   // kT[k][s]; later V rows [s][e]
    __shared__ float ss[64][64];   // Sprev
    __shared__ float ps[64][68];   // masked P [t][s]

    const size_t base = ((size_t)bh * LSEQ + (size_t)c * CHUNK) * DHEAD;
    const size_t sbase = ((size_t)bh * NC + c) * (DHEAD * DHEAD);
    const float* zp = zpre + ((size_t)bh * NC + c) * 64;

#pragma unroll
    for (int i = 0; i < 2; ++i) {
        int id  = tid + i * 256;
        int row = id >> 3;          // 0..63
        int cg  = (id & 7) * 8;     // 0..56
        bf16x8 qv = *(const bf16x8*)(qp + base + row * 64 + cg);
        bf16x8 kv = *(const bf16x8*)(kp + base + row * 64 + cg);
#pragma unroll
        for (int j = 0; j < 8; ++j) {
            qT[cg + j][row] = bf2f((unsigned short)qv[j]);
            kT[cg + j][row] = bf2f((unsigned short)kv[j]);
        }
    }
#pragma unroll
    for (int i = 0; i < 4; ++i) {
        int f = tid + i * 256;
        int row = f >> 4, qd = (f & 15) * 4;
        *(float4*)&ss[row][qd] = *(const float4*)(Spre + sbase + row * 64 + qd);
    }
    __syncthreads();

    float oacc[4][4], pacc[4][4], den[4];
#pragma unroll
    for (int i = 0; i < 4; ++i) {
        den[i] = 0.f;
#pragma unroll
        for (int j = 0; j < 4; ++j) { oacc[i][j] = 0.f; pacc[i][j] = 0.f; }
    }

    for (int k = 0; k < 64; ++k) {
        float a[4], bb[4];
        float4 s4 = *(const float4*)&ss[k][txx * 4];
        float zk = zp[k];
#pragma unroll
        for (int ii = 0; ii < 4; ++ii) a[ii] = qT[k][tyy * 4 + ii];
#pragma unroll
        for (int jj = 0; jj < 4; ++jj) bb[jj] = kT[k][txx * 4 + jj];
#pragma unroll
        for (int ii = 0; ii < 4; ++ii) {
            den[ii] = fmaf(a[ii], zk, den[ii]);
            oacc[ii][0] = fmaf(a[ii], s4.x, oacc[ii][0]);
            oacc[ii][1] = fmaf(a[ii], s4.y, oacc[ii][1]);
            oacc[ii][2] = fmaf(a[ii], s4.z, oacc[ii][2]);
            oacc[ii][3] = fmaf(a[ii], s4.w, oacc[ii][3]);
#pragma unroll
            for (int jj = 0; jj < 4; ++jj)
                pacc[ii][jj] = fmaf(a[ii], bb[jj], pacc[ii][jj]);
        }
    }

#pragma unroll
    for (int ii = 0; ii < 4; ++ii) {
        int t = tyy * 4 + ii;
#pragma unroll
        for (int jj = 0; jj < 4; ++jj) {
            int s = txx * 4 + jj;
            ps[t][s] = (s <= t) ? pacc[ii][jj] : 0.f;
        }
    }
    __syncthreads();   // done with kT as K; ps complete

    // reload V row-major into kT ([s][e], stride 65)
#pragma unroll
    for (int i = 0; i < 2; ++i) {
        int id  = tid + i * 256;
        int row = id >> 3;
        int cg  = (id & 7) * 8;
        bf16x8 vv = *(const bf16x8*)(vp + base + row * 64 + cg);
#pragma unroll
        for (int j = 0; j < 8; ++j)
            kT[row][cg + j] = bf2f((unsigned short)vv[j]);
    }
    __syncthreads();

    for (int s = 0; s < 64; ++s) {
        float v0 = kT[s][txx * 4 + 0];
        float v1 = kT[s][txx * 4 + 1];
        float v2 = kT[s][txx * 4 + 2];
        float v3 = kT[s][txx * 4 + 3];
#pragma unroll
        for (int ii = 0; ii < 4; ++ii) {
            float p = ps[tyy * 4 + ii][s];
            den[ii] += p;
            oacc[ii][0] = fmaf(p, v0, oacc[ii][0]);
            oacc[ii][1] = fmaf(p, v1, oacc[ii][1]);
            oacc[ii][2] = fmaf(p, v2, oacc[ii][2]);
            oacc[ii][3] = fmaf(p, v3, oacc[ii][3]);
        }
    }

#pragma unroll
    for (int ii = 0; ii < 4; ++ii) {
        int t = tyy * 4 + ii;
        int l = c * CHUNK + t;
        float inv = 1.f / (den[ii] + EPS_F);
#pragma unroll
        for (int jj = 0; jj < 4; ++jj) {
            int e = txx * 4 + jj;
            att[((size_t)b * LSEQ + l) * DMODEL + h * DHEAD + e] =
                f2bf(oacc[ii][jj] * inv);
        }
    }
}

// =====================================================================
extern "C" void kernel_launch(void* const* d_in, const int* in_sizes, int n_in,
                              void* d_out, int out_size, void* d_ws, size_t ws_size,
                              hipStream_t stream)
{
    const float* query = (const float*)d_in[0];
    const float* key_  = (const float*)d_in[1];
    const float* value = (const float*)d_in[2];
    const float* Wq = (const float*)d_in[3];
    const float* Wk = (const float*)d_in[4];
    const float* Wv = (const float*)d_in[5];
    const float* Wo = (const float*)d_in[6];
    float* out = (float*)d_out;

    const int M  = 2 * LSEQ;     // 2048
    const int BH = 2 * H_HEADS;  // 32
    const int NC = NCHUNK;       // 16

    // ws layout (bytes):
    //   [0,        8.4M)   Wb   : bf16 Wq|Wk|Wv|Wo      4 x 1M x 2B
    //   [8.4M,    21.0M)   qp,kp,vp : bf16 [B,H,L,d]    3 x 2M x 2B
    //   [21.0M,   25.2M)   attb : bf16 [M,1024]         2M x 2B
    //   [25.2M,   37.8M)   Xb   : bf16 q|k|v (dead after proj)
    //   [25.2M,   33.7M)   S,z  : fp32 (alias Xb; written after proj)
    char* wsb = (char*)d_ws;
    unsigned short* Wb   = (unsigned short*)(wsb);
    unsigned short* qp   = (unsigned short*)(wsb + 8388608);
    unsigned short* kp   = (unsigned short*)(wsb + 12582912);
    unsigned short* vp   = (unsigned short*)(wsb + 16777216);
    unsigned short* attb = (unsigned short*)(wsb + 20971520);
    unsigned short* Xb   = (unsigned short*)(wsb + 25165824);
    float*          S    = (float*)(wsb + 25165824);
    float*          z    = (float*)(wsb + 33554432);

    dim3 blk(256);
    convert_kernel<<<dim3(2048, 7), blk, 0, stream>>>(
        query, key_, value, Wq, Wk, Wv, Wo, Xb, Wb);
    mfma_gemm64_kernel<true><<<dim3(DMODEL / 128, M / 64, 3), blk, 0, stream>>>(
        Xb, Wb, qp, kp, vp, nullptr);
    chunk_kv_kernel<<<dim3(NC, BH), blk, 0, stream>>>(kp, vp, S, z, NC);
    prefix_kernel<<<dim3(BH * 16), blk, 0, stream>>>(S, z, NC);
    attn_chunk_kernel<<<dim3(NC, BH), blk, 0, stream>>>(qp, kp, vp, S, z, attb, NC);
    mfma_gemm64_kernel<false><<<dim3(DMODEL / 128, M / 64, 1), blk, 0, stream>>>(
        attb, Wb + 3 * (size_t)DMODEL * DMODEL, nullptr, nullptr, nullptr, out);
}

// Round 7
// 73.929 us; speedup vs baseline: 1.4729x; 1.2564x over previous
//
#include <hip/hip_runtime.h>
#include <hip/hip_bf16.h>
#include <math.h>

#define H_HEADS 16
#define DMODEL  1024
#define DHEAD   64
#define LSEQ    1024
#define CHUNK   64
#define NCHUNK  16
#define EPS_F   1e-6f

typedef __attribute__((ext_vector_type(8))) short bf16x8;   // 8 bf16 = 4 VGPRs
typedef __attribute__((ext_vector_type(4))) float f32x4;    // MFMA 16x16 accumulator

__device__ inline unsigned short f2bf(float f) {
    unsigned int u = __float_as_uint(f);
    u += 0x7FFF + ((u >> 16) & 1);          // round-to-nearest-even
    return (unsigned short)(u >> 16);
}
__device__ inline float bf2f(unsigned short h) {
    return __uint_as_float(((unsigned int)h) << 16);
}

// byte offset into a [64][64]-bf16 LDS tile (128B rows) with T2 XOR swizzle
__device__ inline int swz16(int row, int byteInRow) {
    return row * 128 + (byteInRow ^ ((row & 7) << 4));
}

// async global->LDS, 16B/lane. global src per-lane; LDS dst wave-uniform base.
#define GLOAD16(g, l) __builtin_amdgcn_global_load_lds( \
    (const __attribute__((address_space(1))) void*)(g), \
    (__attribute__((address_space(3))) void*)(l), 16, 0, 0)

// =====================================================================
// fp32 -> bf16 convert: q,k,v -> Xb[3][2M]; Wq,Wk,Wv,Wo -> Wb[4][1M].
// =====================================================================
__global__ __launch_bounds__(256)
void convert_kernel(const float* __restrict__ q, const float* __restrict__ k,
                    const float* __restrict__ v,
                    const float* __restrict__ Wq, const float* __restrict__ Wk,
                    const float* __restrict__ Wv, const float* __restrict__ Wo,
                    unsigned short* __restrict__ Xb, unsigned short* __restrict__ Wb)
{
    const int y = blockIdx.y;
    const float* src;
    unsigned short* dst;
    int n;
    if (y < 3) {
        src = (y == 0) ? q : (y == 1) ? k : v;
        dst = Xb + (size_t)y * (2 * LSEQ * DMODEL);
        n = 2 * LSEQ * DMODEL;
    } else {
        int w = y - 3;
        src = (w == 0) ? Wq : (w == 1) ? Wk : (w == 2) ? Wv : Wo;
        dst = Wb + (size_t)w * (DMODEL * DMODEL);
        n = DMODEL * DMODEL;
    }
    int idx = (blockIdx.x * 256 + threadIdx.x) * 4;
    if (idx < n) {
        float4 f = *(const float4*)(src + idx);
        ushort4 h = make_ushort4(f2bf(f.x), f2bf(f.y), f2bf(f.z), f2bf(f.w));
        *(ushort4*)(dst + idx) = h;
    }
}

// =====================================================================
// bf16 MFMA GEMM: BM=64, BN=128, BK=64 (2 subtiles, one barrier pair per
// 64-K), 4 waves (2x2 of 32x64), global_load_lds staging.
// =====================================================================
template<bool PROJ>
__global__ __launch_bounds__(256)
void mfma_gemm64_kernel(const unsigned short* __restrict__ Xb,
                        const unsigned short* __restrict__ Wb,
                        unsigned short* __restrict__ qp,
                        unsigned short* __restrict__ kp,
                        unsigned short* __restrict__ vp,
                        float* __restrict__ outf)
{
    const int z = PROJ ? blockIdx.z : 0;
    const unsigned short* X = PROJ ? (Xb + (size_t)z * (2 * LSEQ * DMODEL)) : Xb;
    const unsigned short* W = PROJ ? (Wb + (size_t)z * (DMODEL * DMODEL)) : Wb;

    __shared__ unsigned short As[2 * 64 * 32];    // 2 subtiles x 4 KB
    __shared__ unsigned short Bs[2 * 128 * 32];   // 2 subtiles x 8 KB

    const int tid  = threadIdx.x;
    const int m0   = blockIdx.y * 64;
    const int n0   = blockIdx.x * 128;
    const int lane = tid & 63;
    const int wid  = tid >> 6;
    const int wm   = (wid >> 1) * 32;
    const int wn   = (wid & 1) * 64;
    const int r16  = lane & 15;
    const int qh   = lane >> 4;

    const int rA  = wid * 16 + (lane >> 2);        // 0..63
    const int rB0 = wid * 32 + (lane >> 2);        // 0..127 (two halves)
    const int c16 = lane & 3;
    const char* srcA  = (const char*)(X + (size_t)(m0 + rA)  * DMODEL) + c16 * 16;
    const char* srcB0 = (const char*)(W + (size_t)(n0 + rB0) * DMODEL) + c16 * 16;
    const char* srcB1 = (const char*)(W + (size_t)(n0 + rB0 + 16) * DMODEL) + c16 * 16;
    char* dstA  = (char*)As + wid * 1024;
    char* dstB0 = (char*)Bs + wid * 2048;
    char* dstB1 = (char*)Bs + wid * 2048 + 1024;

    f32x4 acc[2][4];
#pragma unroll
    for (int i = 0; i < 2; ++i)
#pragma unroll
        for (int j = 0; j < 4; ++j) acc[i][j] = (f32x4)0.0f;

    for (int kt = 0; kt < DMODEL; kt += 64) {
#pragma unroll
        for (int hh = 0; hh < 2; ++hh) {
            size_t go = (size_t)(kt + hh * 32) * 2;
            GLOAD16(srcA  + go, dstA  + hh * 4096);
            GLOAD16(srcB0 + go, dstB0 + hh * 8192);
            GLOAD16(srcB1 + go, dstB1 + hh * 8192);
        }
        __syncthreads();   // drains vmcnt -> subtiles ready

        bf16x8 af[2][2], bg[2][4];
#pragma unroll
        for (int hh = 0; hh < 2; ++hh) {
#pragma unroll
            for (int fm = 0; fm < 2; ++fm)
                af[hh][fm] = *(const bf16x8*)&As[hh * 2048 + (wm + fm * 16 + r16) * 32 + qh * 8];
#pragma unroll
            for (int fn = 0; fn < 4; ++fn)
                bg[hh][fn] = *(const bf16x8*)&Bs[hh * 4096 + (wn + fn * 16 + r16) * 32 + qh * 8];
        }
#pragma unroll
        for (int hh = 0; hh < 2; ++hh)
#pragma unroll
            for (int fm = 0; fm < 2; ++fm)
#pragma unroll
                for (int fn = 0; fn < 4; ++fn)
                    acc[fm][fn] = __builtin_amdgcn_mfma_f32_16x16x32_bf16(
                        af[hh][fm], bg[hh][fn], acc[fm][fn], 0, 0, 0);
        __syncthreads();
    }

    if (PROJ) {
        unsigned short* O = (z == 0) ? qp : (z == 1) ? kp : vp;
        const float sc = (z < 2) ? 0.125f : 1.f;
#pragma unroll
        for (int fm = 0; fm < 2; ++fm) {
#pragma unroll
            for (int r = 0; r < 4; ++r) {
                int m = m0 + wm + fm * 16 + qh * 4 + r;
                int b = m >> 10, l = m & 1023;
#pragma unroll
                for (int fn = 0; fn < 4; ++fn) {
                    int n = n0 + wn + fn * 16 + r16;
                    int h = n >> 6, e = n & 63;
                    float y = acc[fm][fn][r] * sc;
                    if (z < 2) y = (y > 0.f) ? y + 1.f : __expf(y);
                    O[(((size_t)(b * H_HEADS + h)) * LSEQ + l) * DHEAD + e] = f2bf(y);
                }
            }
        }
    } else {
#pragma unroll
        for (int fm = 0; fm < 2; ++fm) {
#pragma unroll
            for (int r = 0; r < 4; ++r) {
                int m = m0 + wm + fm * 16 + qh * 4 + r;
#pragma unroll
                for (int fn = 0; fn < 4; ++fn) {
                    int n = n0 + wn + fn * 16 + r16;
                    outf[(size_t)m * DMODEL + n] = acc[fm][fn][r];
                }
            }
        }
    }
}

// =====================================================================
// chunk KV sums via MFMA: St_c[e][i] = sum_s V[s][e]*K[s][i]  (fp32 out),
// z_c[i] = sum_s K[s][i] via ones-row MFMA on wave 0.
// grid = (NC, BH), 256 thr.
// =====================================================================
__global__ __launch_bounds__(256)
void chunk_kv_kernel(const unsigned short* __restrict__ kp,
                     const unsigned short* __restrict__ vp,
                     float* __restrict__ St, float* __restrict__ z)
{
    const int c = blockIdx.x, bh = blockIdx.y;
    const int tid = threadIdx.x;
    const int lane = tid & 63;
    const int w = tid >> 6;
    const int r16 = lane & 15, qh = lane >> 4;

    __shared__ unsigned short kT[64 * 64];   // K^T[i][s], swizzled
    __shared__ unsigned short vt[64 * 64];   // V^T[e][s], swizzled

    const size_t base = ((size_t)bh * LSEQ + (size_t)c * CHUNK) * DHEAD;

#pragma unroll
    for (int i = 0; i < 2; ++i) {
        int id  = tid + i * 256;
        int row = id >> 3;          // s
        int cg  = (id & 7) * 8;     // d/e octet
        bf16x8 kv = *(const bf16x8*)(kp + base + row * 64 + cg);
        bf16x8 vv = *(const bf16x8*)(vp + base + row * 64 + cg);
#pragma unroll
        for (int j = 0; j < 8; ++j) {
            *(unsigned short*)((char*)kT + swz16(cg + j, row * 2)) = (unsigned short)kv[j];
            *(unsigned short*)((char*)vt + swz16(cg + j, row * 2)) = (unsigned short)vv[j];
        }
    }
    __syncthreads();

    bf16x8 av[2], bK[2][4];
#pragma unroll
    for (int kk = 0; kk < 2; ++kk) {
        av[kk] = *(const bf16x8*)((char*)vt + swz16(w * 16 + r16, kk * 64 + qh * 16));
#pragma unroll
        for (int fn = 0; fn < 4; ++fn)
            bK[kk][fn] = *(const bf16x8*)((char*)kT + swz16(fn * 16 + r16, kk * 64 + qh * 16));
    }

    f32x4 acc[4];
#pragma unroll
    for (int fn = 0; fn < 4; ++fn) acc[fn] = (f32x4)0.0f;
#pragma unroll
    for (int kk = 0; kk < 2; ++kk)
#pragma unroll
        for (int fn = 0; fn < 4; ++fn)
            acc[fn] = __builtin_amdgcn_mfma_f32_16x16x32_bf16(av[kk], bK[kk][fn], acc[fn], 0, 0, 0);

    const size_t sbase = ((size_t)bh * NCHUNK + c) * (DHEAD * DHEAD);
#pragma unroll
    for (int r = 0; r < 4; ++r) {
        int e = w * 16 + qh * 4 + r;
#pragma unroll
        for (int fn = 0; fn < 4; ++fn)
            St[sbase + (size_t)e * 64 + fn * 16 + r16] = acc[fn][r];
    }

    if (w == 0) {   // z via ones-row MFMA (A = all 1.0 bf16, exact)
        bf16x8 ones;
#pragma unroll
        for (int j = 0; j < 8; ++j) ones[j] = (short)0x3F80;
        f32x4 accz[4];
#pragma unroll
        for (int fn = 0; fn < 4; ++fn) accz[fn] = (f32x4)0.0f;
#pragma unroll
        for (int kk = 0; kk < 2; ++kk)
#pragma unroll
            for (int fn = 0; fn < 4; ++fn)
                accz[fn] = __builtin_amdgcn_mfma_f32_16x16x32_bf16(ones, bK[kk][fn], accz[fn], 0, 0, 0);
        if (qh == 0) {
            const size_t zb = ((size_t)bh * NCHUNK + c) * 64;
#pragma unroll
            for (int fn = 0; fn < 4; ++fn)
                z[zb + fn * 16 + r16] = accz[fn][0];
        }
    }
}

// =====================================================================
// Exclusive prefix over chunks: St fp32 -> stb bf16 (pre-swizzled rows so
// attn can global_load_lds linearly); z scanned fp32 in place.
// grid = BH*16, 256 thr.
// =====================================================================
__global__ __launch_bounds__(256)
void prefix_kernel(const float* __restrict__ St, unsigned short* __restrict__ stb,
                   float* __restrict__ z)
{
    const int bh   = blockIdx.x >> 4;
    const int eblk = blockIdx.x & 15;
    const int idx  = eblk * 256 + threadIdx.x;   // 0..4095
    const int e = idx >> 6, i = idx & 63;

    const size_t ibase = (size_t)bh * NCHUNK * 4096 + idx;
    float v[NCHUNK];
#pragma unroll
    for (int c = 0; c < NCHUNK; ++c)
        v[c] = St[ibase + (size_t)c * 4096];

    const size_t obase = (size_t)bh * NCHUNK * 4096 + e * 64 + (i ^ ((e & 7) << 3));
    float run = 0.f;
#pragma unroll
    for (int c = 0; c < NCHUNK; ++c) {
        stb[obase + (size_t)c * 4096] = f2bf(run);
        run += v[c];
    }

    if (eblk == 0 && threadIdx.x < DHEAD) {
        const size_t zb = (size_t)bh * NCHUNK * DHEAD + threadIdx.x;
        float zv[NCHUNK];
#pragma unroll
        for (int c = 0; c < NCHUNK; ++c)
            zv[c] = z[zb + (size_t)c * DHEAD];
        float zr = 0.f;
#pragma unroll
        for (int c = 0; c < NCHUNK; ++c) {
            z[zb + (size_t)c * DHEAD] = zr;
            zr += zv[c];
        }
    }
}

// =====================================================================
// Per-chunk causal attention, full MFMA:
//   P = Qp@Kp^T (mask, rowsum in C-regs) ; O = Qp@Sprev^T + P@V^T.
//   den = qp.z_prev (pre-pass) + rowsum.  grid = (NC, BH), 256 thr.
// =====================================================================
__global__ __launch_bounds__(256)
void attn_mfma_kernel(const unsigned short* __restrict__ qp,
                      const unsigned short* __restrict__ kp,
                      const unsigned short* __restrict__ vp,
                      const unsigned short* __restrict__ stb,
                      const float* __restrict__ zpre,
                      unsigned short* __restrict__ att)
{
    const int c = blockIdx.x, bh = blockIdx.y;
    const int b = bh >> 4, h = bh & 15;
    const int tid = threadIdx.x;
    const int lane = tid & 63;
    const int w = tid >> 6;
    const int r16 = lane & 15, qh = lane >> 4;

    __shared__ unsigned short qs[64 * 64];   // Qp[t][d] swizzled
    __shared__ unsigned short ks[64 * 64];   // Kp[s][d] swizzled
    __shared__ unsigned short vt[64 * 64];   // V^T[e][s] swizzled
    __shared__ unsigned short stl[64 * 64];  // Sprev^T[e][i] (global pre-swizzled)
    __shared__ unsigned short ps[64 * 64];   // masked P[t][s] swizzled
    __shared__ float denl[64];

    const size_t base = ((size_t)bh * LSEQ + (size_t)c * CHUNK) * DHEAD;
    const unsigned short* stg = stb + ((size_t)bh * NCHUNK + c) * 4096;
    const float* zp = zpre + ((size_t)bh * NCHUNK + c) * 64;

    // stage Sprev^T via gload (global rows pre-swizzled by prefix_kernel)
    {
        const char* src = (const char*)stg + w * 2048 + lane * 16;
        GLOAD16(src,        (char*)stl + w * 2048);
        GLOAD16(src + 1024, (char*)stl + w * 2048 + 1024);
    }
    // stage Qp, Kp natural; V transposed
#pragma unroll
    for (int i = 0; i < 2; ++i) {
        int id  = tid + i * 256;
        int row = id >> 3;
        int cg  = (id & 7) * 8;
        bf16x8 qv = *(const bf16x8*)(qp + base + row * 64 + cg);
        bf16x8 kv = *(const bf16x8*)(kp + base + row * 64 + cg);
        *(bf16x8*)((char*)qs + swz16(row, cg * 2)) = qv;
        *(bf16x8*)((char*)ks + swz16(row, cg * 2)) = kv;
        bf16x8 vv = *(const bf16x8*)(vp + base + row * 64 + cg);
#pragma unroll
        for (int j = 0; j < 8; ++j)
            *(unsigned short*)((char*)vt + swz16(cg + j, row * 2)) = (unsigned short)vv[j];
    }
    // den1[t] = qp_row_t . z_prev  (4 lanes per row)
    {
        int t = tid >> 2, kq = tid & 3;
        const unsigned short* qrow = qp + base + t * 64 + kq * 16;
        bf16x8 a0 = *(const bf16x8*)(qrow);
        bf16x8 a1 = *(const bf16x8*)(qrow + 8);
        float s = 0.f;
#pragma unroll
        for (int j = 0; j < 8; ++j) {
            s = fmaf(bf2f((unsigned short)a0[j]), zp[kq * 16 + j], s);
            s = fmaf(bf2f((unsigned short)a1[j]), zp[kq * 16 + 8 + j], s);
        }
        s += __shfl_xor(s, 1);
        s += __shfl_xor(s, 2);
        if (kq == 0) denl[t] = s;
    }
    __syncthreads();   // drains gload (vmcnt) + all LDS staging

    // A-frags of Qp for wave's 16-row slice (shared by P and O1)
    bf16x8 aq[2];
#pragma unroll
    for (int kk = 0; kk < 2; ++kk)
        aq[kk] = *(const bf16x8*)((char*)qs + swz16(w * 16 + r16, kk * 64 + qh * 16));

    // ---- P = Qp @ Kp^T ----
    f32x4 accp[4];
#pragma unroll
    for (int fn = 0; fn < 4; ++fn) accp[fn] = (f32x4)0.0f;
#pragma unroll
    for (int kk = 0; kk < 2; ++kk)
#pragma unroll
        for (int fn = 0; fn < 4; ++fn) {
            bf16x8 bk = *(const bf16x8*)((char*)ks + swz16(fn * 16 + r16, kk * 64 + qh * 16));
            accp[fn] = __builtin_amdgcn_mfma_f32_16x16x32_bf16(aq[kk], bk, accp[fn], 0, 0, 0);
        }

    // mask (causal within chunk), rowsum, write bf16 P to LDS
    float rs[4];
#pragma unroll
    for (int r = 0; r < 4; ++r) {
        int t_loc = w * 16 + qh * 4 + r;
        float rsum = 0.f;
#pragma unroll
        for (int fn = 0; fn < 4; ++fn) {
            int s_loc = fn * 16 + r16;
            float p = (s_loc <= t_loc) ? accp[fn][r] : 0.f;
            rsum += p;
            *(unsigned short*)((char*)ps + swz16(t_loc, s_loc * 2)) = f2bf(p);
        }
        rsum += __shfl_xor(rsum, 1);
        rsum += __shfl_xor(rsum, 2);
        rsum += __shfl_xor(rsum, 4);
        rsum += __shfl_xor(rsum, 8);
        rs[r] = rsum;
    }

    // ---- O = Qp @ Sprev^T + P @ V^T ----
    f32x4 acc[4];
#pragma unroll
    for (int fn = 0; fn < 4; ++fn) acc[fn] = (f32x4)0.0f;
#pragma unroll
    for (int kk = 0; kk < 2; ++kk)
#pragma unroll
        for (int fn = 0; fn < 4; ++fn) {
            bf16x8 bs = *(const bf16x8*)((char*)stl + swz16(fn * 16 + r16, kk * 64 + qh * 16));
            acc[fn] = __builtin_amdgcn_mfma_f32_16x16x32_bf16(aq[kk], bs, acc[fn], 0, 0, 0);
        }
    bf16x8 ap[2];
#pragma unroll
    for (int kk = 0; kk < 2; ++kk)
        ap[kk] = *(const bf16x8*)((char*)ps + swz16(w * 16 + r16, kk * 64 + qh * 16));
#pragma unroll
    for (int kk = 0; kk < 2; ++kk)
#pragma unroll
        for (int fn = 0; fn < 4; ++fn) {
            bf16x8 bv = *(const bf16x8*)((char*)vt + swz16(fn * 16 + r16, kk * 64 + qh * 16));
            acc[fn] = __builtin_amdgcn_mfma_f32_16x16x32_bf16(ap[kk], bv, acc[fn], 0, 0, 0);
        }

    // epilogue: divide by den, store bf16 att [B, L, D]
#pragma unroll
    for (int r = 0; r < 4; ++r) {
        int t_loc = w * 16 + qh * 4 + r;
        int l = c * CHUNK + t_loc;
        float inv = 1.f / (denl[t_loc] + rs[r] + EPS_F);
#pragma unroll
        for (int fn = 0; fn < 4; ++fn) {
            int e = fn * 16 + r16;
            att[((size_t)b * LSEQ + l) * DMODEL + h * DHEAD + e] = f2bf(acc[fn][r] * inv);
        }
    }
}

// =====================================================================
extern "C" void kernel_launch(void* const* d_in, const int* in_sizes, int n_in,
                              void* d_out, int out_size, void* d_ws, size_t ws_size,
                              hipStream_t stream)
{
    const float* query = (const float*)d_in[0];
    const float* key_  = (const float*)d_in[1];
    const float* value = (const float*)d_in[2];
    const float* Wq = (const float*)d_in[3];
    const float* Wk = (const float*)d_in[4];
    const float* Wv = (const float*)d_in[5];
    const float* Wo = (const float*)d_in[6];
    float* out = (float*)d_out;

    const int M  = 2 * LSEQ;     // 2048
    const int BH = 2 * H_HEADS;  // 32

    // ws layout (bytes):
    //   [0,        8.4M)   Wb   : bf16 Wq|Wk|Wv|Wo
    //   [8.4M,    21.0M)   qp,kp,vp : bf16 [B,H,L,d]
    //   [21.0M,   25.2M)   attb : bf16 [M,1024]
    //   [25.2M,   37.75M)  Xb   : bf16 q|k|v (dead after proj)
    //   [25.2M,   33.55M)  St   : fp32 S^T chunk sums (alias Xb)
    //   [33.55M,  33.69M)  z    : fp32
    //   [33.69M,  37.88M)  stb  : bf16 S_prev^T pre-swizzled
    char* wsb = (char*)d_ws;
    unsigned short* Wb   = (unsigned short*)(wsb);
    unsigned short* qp   = (unsigned short*)(wsb + 8388608);
    unsigned short* kp   = (unsigned short*)(wsb + 12582912);
    unsigned short* vp   = (unsigned short*)(wsb + 16777216);
    unsigned short* attb = (unsigned short*)(wsb + 20971520);
    unsigned short* Xb   = (unsigned short*)(wsb + 25165824);
    float*          St   = (float*)(wsb + 25165824);
    float*          z    = (float*)(wsb + 33554432);
    unsigned short* stb  = (unsigned short*)(wsb + 33685504);

    dim3 blk(256);
    convert_kernel<<<dim3(2048, 7), blk, 0, stream>>>(
        query, key_, value, Wq, Wk, Wv, Wo, Xb, Wb);
    mfma_gemm64_kernel<true><<<dim3(DMODEL / 128, M / 64, 3), blk, 0, stream>>>(
        Xb, Wb, qp, kp, vp, nullptr);
    chunk_kv_kernel<<<dim3(NCHUNK, BH), blk, 0, stream>>>(kp, vp, St, z);
    prefix_kernel<<<dim3(BH * 16), blk, 0, stream>>>(St, stb, z);
    attn_mfma_kernel<<<dim3(NCHUNK, BH), blk, 0, stream>>>(qp, kp, vp, stb, z, attb);
    mfma_gemm64_kernel<false><<<dim3(DMODEL / 128, M / 64, 1), blk, 0, stream>>>(
        attb, Wb + 3 * (size_t)DMODEL * DMODEL, nullptr, nullptr, nullptr, out);
}